// Round 3
// baseline (638.040 us; speedup 1.0000x reference)
//
#include <hip/hip_runtime.h>

// AttentionHead: B=8, S1=S2=2048, E=P=1024. Inputs fp32 (reference dtypes),
// OUTPUT fp32 (reference output dtype -> d_out is float*). Compute in bf16
// MFMA with fp32 accumulation.
//   canonicalize inputs -> bf16 (detector guards against bf16-input harness)
//   q  = query @ W^T + b            (16384x1024x1024)  -> ws (bf16)
//   k  = key   @ W^T + b            (16384x1024x1024)  -> ws (bf16)
//   vT = (value @ W^T + b)^T        (stored [b][p][s2]) -> ws (bf16)
//   S  = softmax( q k^T / 32 )      per batch, bf16 in-place in ws
//   out= S @ vT^T                   per batch -> d_out (fp32)

typedef unsigned short u16;
typedef __bf16 bf16x8 __attribute__((ext_vector_type(8)));
typedef float f32x4 __attribute__((ext_vector_type(4)));

__device__ __forceinline__ float b2f(u16 u) {
    union { unsigned i; float f; } x; x.i = ((unsigned)u) << 16; return x.f;
}
// round-to-nearest-even f32 -> bf16
__device__ __forceinline__ u16 f2b(float f) {
    union { float f; unsigned i; } x; x.f = f;
    unsigned r = x.i + 0x7FFFu + ((x.i >> 16) & 1u);
    return (u16)(r >> 16);
}

// ---- dtype detector: 1 block x 64 threads. Reads first 64 words of query.
// bf16 data: low half of each word is a real N(0,1) bf16 -> exponent in
// [112,131] ~always. fp32 data: low 16 bits are random mantissa -> ~8%.
// flag: 0=bf16, 1=fp32.
__global__ void detect_dtype(const unsigned* __restrict__ q, int* __restrict__ flag)
{
    int lane = threadIdx.x;
    unsigned w = q[lane];
    unsigned e = (w >> 7) & 0xFFu;
    int plaus = (e >= 112u && e <= 131u) ? 1 : 0;
#pragma unroll
    for (int o = 32; o; o >>= 1) plaus += __shfl_xor(plaus, o, 64);
    if (lane == 0) *flag = (plaus >= 32) ? 0 : 1;
}

// ---- canonicalize to bf16: cast fp32 (flag=1) or copy bf16 (flag=0).
__global__ __launch_bounds__(256)
void convert_bf16(const void* __restrict__ src, u16* __restrict__ dst,
                  long n, const int* __restrict__ flag)
{
    long i = ((long)blockIdx.x * 256 + threadIdx.x) * 8;
    if (i >= n) return;
    if (*flag) {
        const float4* s = (const float4*)((const float*)src + i);
        float4 a = s[0], b = s[1];
        ushort4 lo, hi;
        lo.x = f2b(a.x); lo.y = f2b(a.y); lo.z = f2b(a.z); lo.w = f2b(a.w);
        hi.x = f2b(b.x); hi.y = f2b(b.y); hi.z = f2b(b.z); hi.w = f2b(b.w);
        *(ushort4*)(dst + i) = lo;
        *(ushort4*)(dst + i + 4) = hi;
    } else {
        uint4 v = *(const uint4*)((const u16*)src + i);
        *(uint4*)(dst + i) = v;
    }
}

#define BM 128
#define BN 128
#define BK 64

// C = alpha * (A B^T) + bias;  A:(M,K) row-major lda=K, B:(N,K) row-major ldb=K.
// mode 0: C bf16 row-major, ldc; batch offset zC*z
// mode 1: C fp32 row-major, ldc; batch offset zC*z   (final output)
// mode 2: vT store: C[(row>>11)*2048*1024 + col*2048 + (row&2047)] bf16
__global__ __launch_bounds__(256)
void gemm_nt(const u16* __restrict__ A, const u16* __restrict__ B,
             void* __restrict__ C, const u16* __restrict__ bias,
             int M, int N, int K, float alpha, int mode, int ldc,
             long zA, long zB, long zC)
{
    __shared__ __align__(16) u16 lds[2 * BM * BK];   // 32 KB
    u16* As = lds;
    u16* Bs = lds + BM * BK;

    const int z = blockIdx.z;
    A += zA * z;
    B += zB * z;
    const long coff = zC * z;

    const int tid  = threadIdx.x;
    const int wave = tid >> 6, lane = tid & 63;
    const int wm = wave >> 1, wn = wave & 1;          // 2x2 wave grid, 64x64 each
    const int quad = lane >> 4, l15 = lane & 15;

    const int bm0 = blockIdx.y * BM;
    const int bn0 = blockIdx.x * BN;

    f32x4 acc[4][4];
#pragma unroll
    for (int i = 0; i < 4; i++)
#pragma unroll
        for (int j = 0; j < 4; j++) acc[i][j] = f32x4{0.f, 0.f, 0.f, 0.f};

    // staging: lane offsets are lane-contiguous (lane*16B from wave base),
    // matching global_load_lds wave-uniform-base semantics.
    const int stg_r = wave * 8 + (lane >> 3);        // 0..31
    const int stg_c = (lane & 7) * 8;

    for (int kt = 0; kt < K; kt += BK) {
#pragma unroll
        for (int i = 0; i < 4; i++) {
            const int r = i * 32 + stg_r;            // 0..127
            __builtin_amdgcn_global_load_lds(
                (const __attribute__((address_space(1))) void*)(A + (long)(bm0 + r) * K + kt + stg_c),
                (__attribute__((address_space(3))) void*)(As + r * BK + stg_c),
                16, 0, 0);
            __builtin_amdgcn_global_load_lds(
                (const __attribute__((address_space(1))) void*)(B + (long)(bn0 + r) * K + kt + stg_c),
                (__attribute__((address_space(3))) void*)(Bs + r * BK + stg_c),
                16, 0, 0);
        }
        __syncthreads();

#pragma unroll
        for (int kk = 0; kk < 2; kk++) {
            const int ko = kk * 32 + quad * 8;
            bf16x8 af[4], bb[4];
#pragma unroll
            for (int t = 0; t < 4; t++)
                af[t] = *(const bf16x8*)(As + (wm * 64 + t * 16 + l15) * BK + ko);
#pragma unroll
            for (int t = 0; t < 4; t++)
                bb[t] = *(const bf16x8*)(Bs + (wn * 64 + t * 16 + l15) * BK + ko);
#pragma unroll
            for (int mt = 0; mt < 4; mt++)
#pragma unroll
                for (int nt = 0; nt < 4; nt++)
                    acc[mt][nt] = __builtin_amdgcn_mfma_f32_16x16x32_bf16(
                        af[mt], bb[nt], acc[mt][nt], 0, 0, 0);
        }
        __syncthreads();
    }

    // epilogue; C/D layout: col = lane&15, row = quad*4 + reg (m89/m91)
#pragma unroll
    for (int mt = 0; mt < 4; mt++) {
        const int row = bm0 + wm * 64 + mt * 16 + quad * 4;
#pragma unroll
        for (int nt = 0; nt < 4; nt++) {
            const int col = bn0 + wn * 64 + nt * 16 + l15;
            const float bv = bias ? b2f(bias[col]) : 0.f;
            f32x4 v = acc[mt][nt];
            float o0 = alpha * v[0] + bv;
            float o1 = alpha * v[1] + bv;
            float o2 = alpha * v[2] + bv;
            float o3 = alpha * v[3] + bv;
            if (mode == 2) {
                // vT[batch][p=col][s=row&2047], 4 consecutive s -> 8B store
                ushort4 pk;
                pk.x = f2b(o0); pk.y = f2b(o1); pk.z = f2b(o2); pk.w = f2b(o3);
                *(ushort4*)((u16*)C + ((long)(row >> 11) << 21) + ((long)col << 11) + (row & 2047)) = pk;
            } else if (mode == 1) {
                float* Cf = (float*)C + coff;
                Cf[(long)(row + 0) * ldc + col] = o0;
                Cf[(long)(row + 1) * ldc + col] = o1;
                Cf[(long)(row + 2) * ldc + col] = o2;
                Cf[(long)(row + 3) * ldc + col] = o3;
            } else {
                u16* Cb = (u16*)C + coff;
                Cb[(long)(row + 0) * ldc + col] = f2b(o0);
                Cb[(long)(row + 1) * ldc + col] = f2b(o1);
                Cb[(long)(row + 2) * ldc + col] = f2b(o2);
                Cb[(long)(row + 3) * ldc + col] = f2b(o3);
            }
        }
    }
}

// in-place softmax over rows of 2048 bf16; one block (256 thr) per row
__global__ __launch_bounds__(256)
void softmax_rows(u16* __restrict__ S)
{
    const long row = blockIdx.x;
    u16* p = S + (row << 11);
    const int tid = threadIdx.x, wave = tid >> 6, lane = tid & 63;

    union { uint4 q; u16 u[8]; } d;
    d.q = ((const uint4*)p)[tid];
    float v[8];
#pragma unroll
    for (int i = 0; i < 8; i++) v[i] = b2f(d.u[i]);

    float m = v[0];
#pragma unroll
    for (int i = 1; i < 8; i++) m = fmaxf(m, v[i]);
#pragma unroll
    for (int o = 32; o; o >>= 1) m = fmaxf(m, __shfl_xor(m, o, 64));
    __shared__ float redm[4], reds[4];
    if (lane == 0) redm[wave] = m;
    __syncthreads();
    m = fmaxf(fmaxf(redm[0], redm[1]), fmaxf(redm[2], redm[3]));

    float e[8], s = 0.f;
#pragma unroll
    for (int i = 0; i < 8; i++) { e[i] = __expf(v[i] - m); s += e[i]; }
#pragma unroll
    for (int o = 32; o; o >>= 1) s += __shfl_xor(s, o, 64);
    if (lane == 0) reds[wave] = s;
    __syncthreads();
    s = reds[0] + reds[1] + reds[2] + reds[3];

    const float inv = 1.f / s;
#pragma unroll
    for (int i = 0; i < 8; i++) d.u[i] = f2b(e[i] * inv);
    ((uint4*)p)[tid] = d.q;
}

extern "C" void kernel_launch(void* const* d_in, const int* in_sizes, int n_in,
                              void* d_out, int out_size, void* d_ws, size_t ws_size,
                              hipStream_t stream) {
    const void* query = d_in[0];   // (8,2048,1024) fp32
    const void* key   = d_in[1];
    const void* value = d_in[2];
    const void* W     = d_in[3];   // (1024,1024) fp32, row-major (P,E)
    const void* bias  = d_in[4];   // (1024,) fp32
    float* out = (float*)d_out;    // (8,2048,1024) fp32

    // ws layout (u16 elements). Conversion scratch aliases the scores buffer
    // (tmp/Wc/bc/flag all dead before scores GEMM writes sc). Total 167.8 MB.
    //   [0, 33.5M)     sc (scores) | also: tmp [0,16.7M), Wc, bc, flag
    //   [33.5M, 50.3M) qb | [50.3M, 67.1M) kb | [67.1M, 83.9M) vT
    u16* sc  = (u16*)d_ws;
    u16* tmp = (u16*)d_ws;
    u16* Wc  = tmp + 16777216L;
    u16* bc  = Wc + 1048576L;
    int* flag = (int*)(bc + 1024);
    u16* qb  = (u16*)d_ws + 33554432L;
    u16* kb  = qb + 16777216L;
    u16* vT  = kb + 16777216L;

    const dim3 blk(256);

    detect_dtype<<<dim3(1), dim3(64), 0, stream>>>((const unsigned*)query, flag);

    convert_bf16<<<dim3(512), blk, 0, stream>>>(W, Wc, 1048576L, flag);
    convert_bf16<<<dim3(1), blk, 0, stream>>>(bias, bc, 1024L, flag);

    // projections: M=16384 (B*S), N=1024, K=1024; tmp reused per input
    convert_bf16<<<dim3(8192), blk, 0, stream>>>(query, tmp, 16777216L, flag);
    gemm_nt<<<dim3(8, 128, 1), blk, 0, stream>>>(tmp, Wc, qb, bc,
        16384, 1024, 1024, 1.f, 0, 1024, 0, 0, 0);

    convert_bf16<<<dim3(8192), blk, 0, stream>>>(key, tmp, 16777216L, flag);
    gemm_nt<<<dim3(8, 128, 1), blk, 0, stream>>>(tmp, Wc, kb, bc,
        16384, 1024, 1024, 1.f, 0, 1024, 0, 0, 0);

    convert_bf16<<<dim3(8192), blk, 0, stream>>>(value, tmp, 16777216L, flag);
    gemm_nt<<<dim3(8, 128, 1), blk, 0, stream>>>(tmp, Wc, vT, bc,
        16384, 1024, 1024, 1.f, 2, 0, 0, 0, 0);

    // scores: per batch, M=N=2048, K=1024, alpha = 1/sqrt(1024)
    gemm_nt<<<dim3(16, 16, 8), blk, 0, stream>>>(qb, kb, sc, nullptr,
        2048, 2048, 1024, 0.03125f, 0, 2048,
        2048L * 1024, 2048L * 1024, 2048L * 2048);

    // softmax rows (8*2048 rows), in place
    softmax_rows<<<dim3(16384), blk, 0, stream>>>(sc);

    // out = S @ vT^T : per batch, M=2048, N=1024, K=2048, fp32 output
    gemm_nt<<<dim3(8, 16, 8), blk, 0, stream>>>(sc, vT, out, nullptr,
        2048, 1024, 2048, 1.f, 1, 1024,
        2048L * 2048, 1024L * 2048, 2048L * 1024);
}

// Round 4
// 621.864 us; speedup vs baseline: 1.0260x; 1.0260x over previous
//
#include <hip/hip_runtime.h>

// AttentionHead: B=8, S1=S2=2048, E=P=1024. Inputs fp32, output fp32.
// bf16 MFMA compute, fp32 accum. XOR-swizzled LDS (this round): kills the
// 128B-row-stride bank aliasing on ds_read_b128 while keeping the
// lane-contiguous LDS destinations global_load_lds requires.
//   q  = query @ W^T + b            -> ws (bf16)
//   k  = key   @ W^T + b            -> ws (bf16)
//   vT = (value @ W^T + b)^T        -> ws (bf16, [b][p][s2])
//   S  = softmax( q k^T / 32 )      bf16 in-place
//   out= S @ vT^T                   -> d_out (fp32)

typedef unsigned short u16;
typedef __bf16 bf16x8 __attribute__((ext_vector_type(8)));
typedef float f32x4 __attribute__((ext_vector_type(4)));

__device__ __forceinline__ float b2f(u16 u) {
    union { unsigned i; float f; } x; x.i = ((unsigned)u) << 16; return x.f;
}
// round-to-nearest-even f32 -> bf16
__device__ __forceinline__ u16 f2b(float f) {
    union { float f; unsigned i; } x; x.f = f;
    unsigned r = x.i + 0x7FFFu + ((x.i >> 16) & 1u);
    return (u16)(r >> 16);
}

// ---- dtype detector (kept as input-dtype guard): flag 0=bf16, 1=fp32.
__global__ void detect_dtype(const unsigned* __restrict__ q, int* __restrict__ flag)
{
    int lane = threadIdx.x;
    unsigned w = q[lane];
    unsigned e = (w >> 7) & 0xFFu;
    int plaus = (e >= 112u && e <= 131u) ? 1 : 0;
#pragma unroll
    for (int o = 32; o; o >>= 1) plaus += __shfl_xor(plaus, o, 64);
    if (lane == 0) *flag = (plaus >= 32) ? 0 : 1;
}

// ---- canonicalize to bf16
__global__ __launch_bounds__(256)
void convert_bf16(const void* __restrict__ src, u16* __restrict__ dst,
                  long n, const int* __restrict__ flag)
{
    long i = ((long)blockIdx.x * 256 + threadIdx.x) * 8;
    if (i >= n) return;
    if (*flag) {
        const float4* s = (const float4*)((const float*)src + i);
        float4 a = s[0], b = s[1];
        ushort4 lo, hi;
        lo.x = f2b(a.x); lo.y = f2b(a.y); lo.z = f2b(a.z); lo.w = f2b(a.w);
        hi.x = f2b(b.x); hi.y = f2b(b.y); hi.z = f2b(b.z); hi.w = f2b(b.w);
        *(ushort4*)(dst + i) = lo;
        *(ushort4*)(dst + i + 4) = hi;
    } else {
        uint4 v = *(const uint4*)((const u16*)src + i);
        *(uint4*)(dst + i) = v;
    }
}

#define BM 128
#define BN 128
#define BK 64

// C = alpha * (A B^T) + bias;  A:(M,K) lda=K, B:(N,K) ldb=K, row-major.
// mode 0: C bf16 row-major ldc (+ zC*z). mode 1: C fp32 row-major ldc (+ zC*z).
// mode 2: vT store C[(row>>11)*2048*1024 + col*2048 + (row&2047)] bf16.
//
// LDS swizzle: LDS(row, chunk c) holds global 16B-chunk (c ^ (row&7)).
// Staging: lane fetches global chunk ((lane&7) ^ (lane>>3)) into LDS chunk
// (lane&7); row&7 == lane>>3 for every staging instruction. Fragment reads
// fetch LDS chunk (want ^ (l15&7)). Bank-conflict-free both directions.
__global__ __launch_bounds__(256)
void gemm_nt(const u16* __restrict__ A, const u16* __restrict__ B,
             void* __restrict__ C, const u16* __restrict__ bias,
             int M, int N, int K, float alpha, int mode, int ldc,
             long zA, long zB, long zC)
{
    __shared__ __align__(16) u16 lds[2 * BM * BK];   // 32 KB
    u16* As = lds;
    u16* Bs = lds + BM * BK;

    const int z = blockIdx.z;
    A += zA * z;
    B += zB * z;
    const long coff = zC * z;

    const int tid  = threadIdx.x;
    const int wave = tid >> 6, lane = tid & 63;
    const int wm = wave >> 1, wn = wave & 1;          // 2x2 wave grid, 64x64 each
    const int quad = lane >> 4, l15 = lane & 15;
    const int sw = l15 & 7;                           // fragment-read swizzle key

    const int bm0 = blockIdx.y * BM;
    const int bn0 = blockIdx.x * BN;

    f32x4 acc[4][4];
#pragma unroll
    for (int i = 0; i < 4; i++)
#pragma unroll
        for (int j = 0; j < 4; j++) acc[i][j] = f32x4{0.f, 0.f, 0.f, 0.f};

    const int stg_r   = wave * 8 + (lane >> 3);       // tile row 0..31 (+i*32)
    const int stg_cg  = ((lane & 7) ^ (lane >> 3)) * 8; // global chunk (swizzled)
    const int stg_cl  = (lane & 7) * 8;               // LDS chunk (contiguous)

    for (int kt = 0; kt < K; kt += BK) {
#pragma unroll
        for (int i = 0; i < 4; i++) {
            const int r = i * 32 + stg_r;             // 0..127; r&7 == lane>>3
            __builtin_amdgcn_global_load_lds(
                (const __attribute__((address_space(1))) void*)(A + (long)(bm0 + r) * K + kt + stg_cg),
                (__attribute__((address_space(3))) void*)(As + r * BK + stg_cl),
                16, 0, 0);
            __builtin_amdgcn_global_load_lds(
                (const __attribute__((address_space(1))) void*)(B + (long)(bn0 + r) * K + kt + stg_cg),
                (__attribute__((address_space(3))) void*)(Bs + r * BK + stg_cl),
                16, 0, 0);
        }
        __syncthreads();

#pragma unroll
        for (int kk = 0; kk < 2; kk++) {
            bf16x8 af[4], bb[4];
#pragma unroll
            for (int t = 0; t < 4; t++)
                af[t] = *(const bf16x8*)(As + (wm * 64 + t * 16 + l15) * BK
                                             + (((kk * 4 + quad) ^ sw) * 8));
#pragma unroll
            for (int t = 0; t < 4; t++)
                bb[t] = *(const bf16x8*)(Bs + (wn * 64 + t * 16 + l15) * BK
                                             + (((kk * 4 + quad) ^ sw) * 8));
#pragma unroll
            for (int mt = 0; mt < 4; mt++)
#pragma unroll
                for (int nt = 0; nt < 4; nt++)
                    acc[mt][nt] = __builtin_amdgcn_mfma_f32_16x16x32_bf16(
                        af[mt], bb[nt], acc[mt][nt], 0, 0, 0);
        }
        __syncthreads();
    }

    // epilogue; C/D layout: col = lane&15, row = quad*4 + reg (m89/m91)
#pragma unroll
    for (int mt = 0; mt < 4; mt++) {
        const int row = bm0 + wm * 64 + mt * 16 + quad * 4;
#pragma unroll
        for (int nt = 0; nt < 4; nt++) {
            const int col = bn0 + wn * 64 + nt * 16 + l15;
            const float bv = bias ? b2f(bias[col]) : 0.f;
            f32x4 v = acc[mt][nt];
            float o0 = alpha * v[0] + bv;
            float o1 = alpha * v[1] + bv;
            float o2 = alpha * v[2] + bv;
            float o3 = alpha * v[3] + bv;
            if (mode == 2) {
                ushort4 pk;
                pk.x = f2b(o0); pk.y = f2b(o1); pk.z = f2b(o2); pk.w = f2b(o3);
                *(ushort4*)((u16*)C + ((long)(row >> 11) << 21) + ((long)col << 11) + (row & 2047)) = pk;
            } else if (mode == 1) {
                float* Cf = (float*)C + coff;
                Cf[(long)(row + 0) * ldc + col] = o0;
                Cf[(long)(row + 1) * ldc + col] = o1;
                Cf[(long)(row + 2) * ldc + col] = o2;
                Cf[(long)(row + 3) * ldc + col] = o3;
            } else {
                u16* Cb = (u16*)C + coff;
                Cb[(long)(row + 0) * ldc + col] = f2b(o0);
                Cb[(long)(row + 1) * ldc + col] = f2b(o1);
                Cb[(long)(row + 2) * ldc + col] = f2b(o2);
                Cb[(long)(row + 3) * ldc + col] = f2b(o3);
            }
        }
    }
}

// in-place softmax over rows of 2048 bf16; one block (256 thr) per row
__global__ __launch_bounds__(256)
void softmax_rows(u16* __restrict__ S)
{
    const long row = blockIdx.x;
    u16* p = S + (row << 11);
    const int tid = threadIdx.x, wave = tid >> 6, lane = tid & 63;

    union { uint4 q; u16 u[8]; } d;
    d.q = ((const uint4*)p)[tid];
    float v[8];
#pragma unroll
    for (int i = 0; i < 8; i++) v[i] = b2f(d.u[i]);

    float m = v[0];
#pragma unroll
    for (int i = 1; i < 8; i++) m = fmaxf(m, v[i]);
#pragma unroll
    for (int o = 32; o; o >>= 1) m = fmaxf(m, __shfl_xor(m, o, 64));
    __shared__ float redm[4], reds[4];
    if (lane == 0) redm[wave] = m;
    __syncthreads();
    m = fmaxf(fmaxf(redm[0], redm[1]), fmaxf(redm[2], redm[3]));

    float e[8], s = 0.f;
#pragma unroll
    for (int i = 0; i < 8; i++) { e[i] = __expf(v[i] - m); s += e[i]; }
#pragma unroll
    for (int o = 32; o; o >>= 1) s += __shfl_xor(s, o, 64);
    if (lane == 0) reds[wave] = s;
    __syncthreads();
    s = reds[0] + reds[1] + reds[2] + reds[3];

    const float inv = 1.f / s;
#pragma unroll
    for (int i = 0; i < 8; i++) d.u[i] = f2b(e[i] * inv);
    ((uint4*)p)[tid] = d.q;
}

extern "C" void kernel_launch(void* const* d_in, const int* in_sizes, int n_in,
                              void* d_out, int out_size, void* d_ws, size_t ws_size,
                              hipStream_t stream) {
    const void* query = d_in[0];   // (8,2048,1024) fp32
    const void* key   = d_in[1];
    const void* value = d_in[2];
    const void* W     = d_in[3];   // (1024,1024) fp32 (P,E)
    const void* bias  = d_in[4];   // (1024,) fp32
    float* out = (float*)d_out;    // (8,2048,1024) fp32

    // ws layout (u16 elems), total 167.8 MB (known-safe):
    //   [0, 33.5M)     sc (scores) | aliased: tmp [0,16.7M), Wc, bc, flag
    //   [33.5M, 50.3M) qb | [50.3M, 67.1M) kb | [67.1M, 83.9M) vT
    u16* sc  = (u16*)d_ws;
    u16* tmp = (u16*)d_ws;
    u16* Wc  = tmp + 16777216L;
    u16* bc  = Wc + 1048576L;
    int* flag = (int*)(bc + 1024);
    u16* qb  = (u16*)d_ws + 33554432L;
    u16* kb  = qb + 16777216L;
    u16* vT  = kb + 16777216L;

    const dim3 blk(256);

    detect_dtype<<<dim3(1), dim3(64), 0, stream>>>((const unsigned*)query, flag);

    convert_bf16<<<dim3(512), blk, 0, stream>>>(W, Wc, 1048576L, flag);
    convert_bf16<<<dim3(1), blk, 0, stream>>>(bias, bc, 1024L, flag);

    // projections: M=16384, N=1024, K=1024
    convert_bf16<<<dim3(8192), blk, 0, stream>>>(query, tmp, 16777216L, flag);
    gemm_nt<<<dim3(8, 128, 1), blk, 0, stream>>>(tmp, Wc, qb, bc,
        16384, 1024, 1024, 1.f, 0, 1024, 0, 0, 0);

    convert_bf16<<<dim3(8192), blk, 0, stream>>>(key, tmp, 16777216L, flag);
    gemm_nt<<<dim3(8, 128, 1), blk, 0, stream>>>(tmp, Wc, kb, bc,
        16384, 1024, 1024, 1.f, 0, 1024, 0, 0, 0);

    convert_bf16<<<dim3(8192), blk, 0, stream>>>(value, tmp, 16777216L, flag);
    gemm_nt<<<dim3(8, 128, 1), blk, 0, stream>>>(tmp, Wc, vT, bc,
        16384, 1024, 1024, 1.f, 2, 0, 0, 0, 0);

    // scores: per batch, M=N=2048, K=1024, alpha = 1/32
    gemm_nt<<<dim3(16, 16, 8), blk, 0, stream>>>(qb, kb, sc, nullptr,
        2048, 2048, 1024, 0.03125f, 0, 2048,
        2048L * 1024, 2048L * 1024, 2048L * 2048);

    // softmax rows (8*2048), in place
    softmax_rows<<<dim3(16384), blk, 0, stream>>>(sc);

    // out = S @ vT^T : per batch, M=2048, N=1024, K=2048, fp32 output
    gemm_nt<<<dim3(8, 16, 8), blk, 0, stream>>>(sc, vT, out, nullptr,
        2048, 1024, 2048, 1.f, 1, 1024,
        2048L * 2048, 1024L * 2048, 2048L * 1024);
}

// Round 5
// 570.489 us; speedup vs baseline: 1.1184x; 1.0901x over previous
//
#include <hip/hip_runtime.h>

// AttentionHead: B=8, S1=S2=2048, E=P=1024. Inputs fp32, output fp32.
// bf16 MFMA compute, fp32 accum, XOR-swizzled LDS (round-4 win, conflicts=0).
// Round 5: (a) merged q/k/v projection reads fp32 A directly (no convert
// kernels), (b) XCD-aware tile mapping for scores/out GEMMs (L2 locality).
//   Wc = bf16(W), bc = bf16(b)
//   [q|k|vT] = proj(query,key,value)  one dispatch, grid z=3, vT transposed
//   S  = softmax( q k^T / 32 )        bf16 in-place
//   out= S @ vT^T                     -> d_out (fp32)

typedef unsigned short u16;
typedef __bf16 bf16x8 __attribute__((ext_vector_type(8)));
typedef float f32x4 __attribute__((ext_vector_type(4)));

__device__ __forceinline__ float b2f(u16 u) {
    union { unsigned i; float f; } x; x.i = ((unsigned)u) << 16; return x.f;
}
__device__ __forceinline__ u16 f2b(float f) {
    union { float f; unsigned i; } x; x.f = f;
    unsigned r = x.i + 0x7FFFu + ((x.i >> 16) & 1u);
    return (u16)(r >> 16);
}

// fp32 -> bf16 pack (for W and bias; inputs are fp32 per reference)
__global__ __launch_bounds__(256)
void convert_f32_bf16(const float* __restrict__ src, u16* __restrict__ dst, long n)
{
    long i = ((long)blockIdx.x * 256 + threadIdx.x) * 8;
    if (i >= n) return;
    const float4* s = (const float4*)(src + i);
    float4 a = s[0], b = s[1];
    ushort4 lo, hi;
    lo.x = f2b(a.x); lo.y = f2b(a.y); lo.z = f2b(a.z); lo.w = f2b(a.w);
    hi.x = f2b(b.x); hi.y = f2b(b.y); hi.z = f2b(b.z); hi.w = f2b(b.w);
    *(ushort4*)(dst + i) = lo;
    *(ushort4*)(dst + i + 4) = hi;
}

#define BM 128
#define BN 128
#define BK 64

// C = alpha*(A B^T) + bias. A:(M,K) lda=K; B:(N,K) ldb=K (bf16, global_load_lds).
// mode 0: C bf16 row-major ldc (+z*zC). mode 1: C fp32 row-major ldc (+z*zC).
// mode 5: merged projection: A = {A0,A1,A2}[z] as fp32; z<2 -> bf16 C at
//         z*zC; z==2 -> transposed vT store at 2*zC + col*2048 + (row&2047),
//         batch (row>>11) stride 2^21.
// LDS swizzle (round 4): LDS(row, chunk c) holds global chunk (c ^ (row&7)).
// pw>0: XCD-aware tile remap — lin%8 (assumed XCD) gets a pw x ph patch.
__global__ __launch_bounds__(256)
void gemm_nt(const void* __restrict__ A0, const void* __restrict__ A1,
             const void* __restrict__ A2in, const u16* __restrict__ Bb,
             void* __restrict__ C, const u16* __restrict__ bias,
             int K, float alpha, int mode, int ldc,
             long zA, long zB, long zC, int pw, int ph)
{
    __shared__ __align__(16) u16 lds[2 * BM * BK];   // 32 KB
    u16* As = lds;
    u16* Bs = lds + BM * BK;

    const int z = blockIdx.z;
    const u16* Bp = Bb + zB * z;
    const long coff = zC * z;

    const int aF32 = (mode == 5);
    const u16*  Ab  = aF32 ? nullptr : ((const u16*)A0 + zA * z);
    const float* A32 = aF32 ? (const float*)(z == 0 ? A0 : (z == 1 ? A1 : A2in))
                            : nullptr;
    const int em = aF32 ? (z == 2 ? 2 : 0) : mode;   // effective epilogue mode

    // tile coords (XCD-aware patch remap when pw>0)
    int tx = blockIdx.x, ty = blockIdx.y;
    if (pw > 0) {
        const int gx = gridDim.x;
        const int lin = ty * gx + tx;
        const int xcd = lin & 7, i = lin >> 3;
        const int pcols = gx / pw;
        const int pr = xcd / pcols, pc = xcd - pr * pcols;
        tx = pc * pw + (i % pw);
        ty = pr * ph + (i / pw);
    }
    const int bm0 = ty * BM;
    const int bn0 = tx * BN;

    const int tid  = threadIdx.x;
    const int wave = tid >> 6, lane = tid & 63;
    const int wm = wave >> 1, wn = wave & 1;
    const int quad = lane >> 4, l15 = lane & 15;
    const int sw = l15 & 7;

    f32x4 acc[4][4];
#pragma unroll
    for (int i = 0; i < 4; i++)
#pragma unroll
        for (int j = 0; j < 4; j++) acc[i][j] = f32x4{0.f, 0.f, 0.f, 0.f};

    const int stg_r  = wave * 8 + (lane >> 3);          // tile row 0..31 (+i*32)
    const int stg_cg = ((lane & 7) ^ (lane >> 3)) * 8;  // global chunk (swizzled)
    const int stg_cl = (lane & 7) * 8;                  // LDS chunk (contiguous)

    for (int kt = 0; kt < K; kt += BK) {
        // B: async bf16 staging
#pragma unroll
        for (int i = 0; i < 4; i++) {
            const int r = i * 32 + stg_r;
            __builtin_amdgcn_global_load_lds(
                (const __attribute__((address_space(1))) void*)(Bp + (long)(bn0 + r) * K + kt + stg_cg),
                (__attribute__((address_space(3))) void*)(Bs + r * BK + stg_cl),
                16, 0, 0);
        }
        // A: bf16 async, or fp32 load+cvt+ds_write (same swizzled slots)
        if (!aF32) {
#pragma unroll
            for (int i = 0; i < 4; i++) {
                const int r = i * 32 + stg_r;
                __builtin_amdgcn_global_load_lds(
                    (const __attribute__((address_space(1))) void*)(Ab + (long)(bm0 + r) * K + kt + stg_cg),
                    (__attribute__((address_space(3))) void*)(As + r * BK + stg_cl),
                    16, 0, 0);
            }
        } else {
#pragma unroll
            for (int i = 0; i < 4; i++) {
                const int r = i * 32 + stg_r;
                const float* s = A32 + (long)(bm0 + r) * K + kt + stg_cg;
                float4 f0 = *(const float4*)s;
                float4 f1 = *(const float4*)(s + 4);
                uint4 pk;
                pk.x = (unsigned)f2b(f0.x) | ((unsigned)f2b(f0.y) << 16);
                pk.y = (unsigned)f2b(f0.z) | ((unsigned)f2b(f0.w) << 16);
                pk.z = (unsigned)f2b(f1.x) | ((unsigned)f2b(f1.y) << 16);
                pk.w = (unsigned)f2b(f1.z) | ((unsigned)f2b(f1.w) << 16);
                *(uint4*)(As + r * BK + stg_cl) = pk;
            }
        }
        __syncthreads();

#pragma unroll
        for (int kk = 0; kk < 2; kk++) {
            bf16x8 af[4], bb[4];
#pragma unroll
            for (int t = 0; t < 4; t++)
                af[t] = *(const bf16x8*)(As + (wm * 64 + t * 16 + l15) * BK
                                             + (((kk * 4 + quad) ^ sw) * 8));
#pragma unroll
            for (int t = 0; t < 4; t++)
                bb[t] = *(const bf16x8*)(Bs + (wn * 64 + t * 16 + l15) * BK
                                             + (((kk * 4 + quad) ^ sw) * 8));
#pragma unroll
            for (int mt = 0; mt < 4; mt++)
#pragma unroll
                for (int nt = 0; nt < 4; nt++)
                    acc[mt][nt] = __builtin_amdgcn_mfma_f32_16x16x32_bf16(
                        af[mt], bb[nt], acc[mt][nt], 0, 0, 0);
        }
        __syncthreads();
    }

    // epilogue; C/D layout: col = lane&15, row = quad*4 + reg (m89/m91)
#pragma unroll
    for (int mt = 0; mt < 4; mt++) {
        const int row = bm0 + wm * 64 + mt * 16 + quad * 4;
#pragma unroll
        for (int nt = 0; nt < 4; nt++) {
            const int col = bn0 + wn * 64 + nt * 16 + l15;
            const float bv = bias ? b2f(bias[col]) : 0.f;
            f32x4 v = acc[mt][nt];
            float o0 = alpha * v[0] + bv;
            float o1 = alpha * v[1] + bv;
            float o2 = alpha * v[2] + bv;
            float o3 = alpha * v[3] + bv;
            if (em == 2) {
                ushort4 pk;
                pk.x = f2b(o0); pk.y = f2b(o1); pk.z = f2b(o2); pk.w = f2b(o3);
                *(ushort4*)((u16*)C + coff + ((long)(row >> 11) << 21) + ((long)col << 11) + (row & 2047)) = pk;
            } else if (em == 1) {
                float* Cf = (float*)C + coff;
                Cf[(long)(row + 0) * ldc + col] = o0;
                Cf[(long)(row + 1) * ldc + col] = o1;
                Cf[(long)(row + 2) * ldc + col] = o2;
                Cf[(long)(row + 3) * ldc + col] = o3;
            } else {
                u16* Cb = (u16*)C + coff;
                Cb[(long)(row + 0) * ldc + col] = f2b(o0);
                Cb[(long)(row + 1) * ldc + col] = f2b(o1);
                Cb[(long)(row + 2) * ldc + col] = f2b(o2);
                Cb[(long)(row + 3) * ldc + col] = f2b(o3);
            }
        }
    }
}

// in-place softmax over rows of 2048 bf16; one block (256 thr) per row
__global__ __launch_bounds__(256)
void softmax_rows(u16* __restrict__ S)
{
    const long row = blockIdx.x;
    u16* p = S + (row << 11);
    const int tid = threadIdx.x, wave = tid >> 6, lane = tid & 63;

    union { uint4 q; u16 u[8]; } d;
    d.q = ((const uint4*)p)[tid];
    float v[8];
#pragma unroll
    for (int i = 0; i < 8; i++) v[i] = b2f(d.u[i]);

    float m = v[0];
#pragma unroll
    for (int i = 1; i < 8; i++) m = fmaxf(m, v[i]);
#pragma unroll
    for (int o = 32; o; o >>= 1) m = fmaxf(m, __shfl_xor(m, o, 64));
    __shared__ float redm[4], reds[4];
    if (lane == 0) redm[wave] = m;
    __syncthreads();
    m = fmaxf(fmaxf(redm[0], redm[1]), fmaxf(redm[2], redm[3]));

    float e[8], s = 0.f;
#pragma unroll
    for (int i = 0; i < 8; i++) { e[i] = __expf(v[i] - m); s += e[i]; }
#pragma unroll
    for (int o = 32; o; o >>= 1) s += __shfl_xor(s, o, 64);
    if (lane == 0) reds[wave] = s;
    __syncthreads();
    s = reds[0] + reds[1] + reds[2] + reds[3];

    const float inv = 1.f / s;
#pragma unroll
    for (int i = 0; i < 8; i++) d.u[i] = f2b(e[i] * inv);
    ((uint4*)p)[tid] = d.q;
}

extern "C" void kernel_launch(void* const* d_in, const int* in_sizes, int n_in,
                              void* d_out, int out_size, void* d_ws, size_t ws_size,
                              hipStream_t stream) {
    const float* query = (const float*)d_in[0];   // (8,2048,1024) fp32
    const float* key   = (const float*)d_in[1];
    const float* value = (const float*)d_in[2];
    const float* W     = (const float*)d_in[3];   // (1024,1024) fp32 (P,E)
    const float* bias  = (const float*)d_in[4];   // (1024,) fp32
    float* out = (float*)d_out;                   // (8,2048,1024) fp32

    // ws (u16 elems), 167.8 MB:
    //   [0, 33.5M)  sc (scores) | aliased early: Wc @16.7M, bc after
    //   [33.5M..)   qb | kb | vT  (3 x 16.7M, contiguous — mode5 relies on it)
    u16* sc  = (u16*)d_ws;
    u16* Wc  = (u16*)d_ws + 16777216L;
    u16* bc  = Wc + 1048576L;
    u16* qb  = (u16*)d_ws + 33554432L;
    u16* kb  = qb + 16777216L;
    u16* vT  = kb + 16777216L;

    const dim3 blk(256);

    convert_f32_bf16<<<dim3(512), blk, 0, stream>>>(W, Wc, 1048576L);
    convert_f32_bf16<<<dim3(1), blk, 0, stream>>>(bias, bc, 1024L);

    // merged projections: per z in {q,k,v}: M=16384, N=1024, K=1024, fp32 A.
    // C base = qb; z stride 16.7M lands z=1 in kb, z=2 transposed into vT.
    gemm_nt<<<dim3(8, 128, 3), blk, 0, stream>>>(query, key, value, Wc, qb, bc,
        1024, 1.f, 5, 1024, 0, 0, 16777216L, 0, 0);

    // scores: per batch, M=N=2048, K=1024, alpha=1/32; XCD patch 8x4
    gemm_nt<<<dim3(16, 16, 8), blk, 0, stream>>>(qb, nullptr, nullptr, kb, sc, nullptr,
        1024, 0.03125f, 0, 2048, 2048L * 1024, 2048L * 1024, 2048L * 2048, 8, 4);

    // softmax rows (8*2048), in place
    softmax_rows<<<dim3(16384), blk, 0, stream>>>(sc);

    // out = S @ vT^T: per batch, M=2048, N=1024, K=2048, fp32 C; XCD patch 4x4
    gemm_nt<<<dim3(8, 16, 8), blk, 0, stream>>>(sc, nullptr, nullptr, vT, out, nullptr,
        2048, 1.f, 1, 1024, 2048L * 2048, 1024L * 2048, 2048L * 1024, 4, 4);
}

// Round 6
// 523.115 us; speedup vs baseline: 1.2197x; 1.0906x over previous
//
#include <hip/hip_runtime.h>

// AttentionHead: B=8, S1=S2=2048, E=P=1024. Inputs fp32, output fp32.
// bf16 MFMA compute, fp32 accum, XOR-swizzled LDS (conflicts=0, round 4).
// Round 6: XCD patch remap applied to the merged projection (pw=8, ph=16) —
// the 8 blocks sharing an A-panel now land on one XCD (L2 reuse), fixing the
// 794 MB over-fetch seen in round 5.
//   Wc = bf16(W), bc = bf16(b)
//   [q|k|vT] = proj(query,key,value)  one dispatch, grid z=3, vT transposed
//   S  = softmax( q k^T / 32 )        bf16 in-place
//   out= S @ vT^T                     -> d_out (fp32)

typedef unsigned short u16;
typedef __bf16 bf16x8 __attribute__((ext_vector_type(8)));
typedef float f32x4 __attribute__((ext_vector_type(4)));

__device__ __forceinline__ float b2f(u16 u) {
    union { unsigned i; float f; } x; x.i = ((unsigned)u) << 16; return x.f;
}
__device__ __forceinline__ u16 f2b(float f) {
    union { float f; unsigned i; } x; x.f = f;
    unsigned r = x.i + 0x7FFFu + ((x.i >> 16) & 1u);
    return (u16)(r >> 16);
}

// fp32 -> bf16 pack (W and bias)
__global__ __launch_bounds__(256)
void convert_f32_bf16(const float* __restrict__ src, u16* __restrict__ dst, long n)
{
    long i = ((long)blockIdx.x * 256 + threadIdx.x) * 8;
    if (i >= n) return;
    const float4* s = (const float4*)(src + i);
    float4 a = s[0], b = s[1];
    ushort4 lo, hi;
    lo.x = f2b(a.x); lo.y = f2b(a.y); lo.z = f2b(a.z); lo.w = f2b(a.w);
    hi.x = f2b(b.x); hi.y = f2b(b.y); hi.z = f2b(b.z); hi.w = f2b(b.w);
    *(ushort4*)(dst + i) = lo;
    *(ushort4*)(dst + i + 4) = hi;
}

#define BM 128
#define BN 128
#define BK 64

// C = alpha*(A B^T) + bias. A:(M,K) lda=K; B:(N,K) ldb=K (bf16 via global_load_lds).
// mode 0: C bf16 row-major ldc (+z*zC). mode 1: C fp32 row-major ldc (+z*zC).
// mode 5: merged projection: A = {A0,A1,A2}[z] fp32; z<2 -> bf16 C at z*zC;
//         z==2 -> transposed vT store (col*2048 + row&2047, batch stride 2^21).
// LDS swizzle: LDS(row, chunk c) holds global chunk (c ^ (row&7)).
// pw>0: XCD patch remap — lin%8 gets a pw x ph tile patch (assumes
// round-robin block->XCD; affects only locality, not correctness).
__global__ __launch_bounds__(256)
void gemm_nt(const void* __restrict__ A0, const void* __restrict__ A1,
             const void* __restrict__ A2in, const u16* __restrict__ Bb,
             void* __restrict__ C, const u16* __restrict__ bias,
             int K, float alpha, int mode, int ldc,
             long zA, long zB, long zC, int pw, int ph)
{
    __shared__ __align__(16) u16 lds[2 * BM * BK];   // 32 KB
    u16* As = lds;
    u16* Bs = lds + BM * BK;

    const int z = blockIdx.z;
    const u16* Bp = Bb + zB * z;
    const long coff = zC * z;

    const int aF32 = (mode == 5);
    const u16*  Ab  = aF32 ? nullptr : ((const u16*)A0 + zA * z);
    const float* A32 = aF32 ? (const float*)(z == 0 ? A0 : (z == 1 ? A1 : A2in))
                            : nullptr;
    const int em = aF32 ? (z == 2 ? 2 : 0) : mode;   // effective epilogue mode

    // tile coords (XCD-aware patch remap when pw>0)
    int tx = blockIdx.x, ty = blockIdx.y;
    if (pw > 0) {
        const int gx = gridDim.x;
        const int lin = ty * gx + tx;
        const int xcd = lin & 7, i = lin >> 3;
        const int pcols = gx / pw;
        const int pr = xcd / pcols, pc = xcd - pr * pcols;
        tx = pc * pw + (i % pw);
        ty = pr * ph + (i / pw);
    }
    const int bm0 = ty * BM;
    const int bn0 = tx * BN;

    const int tid  = threadIdx.x;
    const int wave = tid >> 6, lane = tid & 63;
    const int wm = wave >> 1, wn = wave & 1;
    const int quad = lane >> 4, l15 = lane & 15;
    const int sw = l15 & 7;

    f32x4 acc[4][4];
#pragma unroll
    for (int i = 0; i < 4; i++)
#pragma unroll
        for (int j = 0; j < 4; j++) acc[i][j] = f32x4{0.f, 0.f, 0.f, 0.f};

    const int stg_r  = wave * 8 + (lane >> 3);          // tile row 0..31 (+i*32)
    const int stg_cg = ((lane & 7) ^ (lane >> 3)) * 8;  // global chunk (swizzled)
    const int stg_cl = (lane & 7) * 8;                  // LDS chunk (contiguous)

    for (int kt = 0; kt < K; kt += BK) {
        // B: async bf16 staging
#pragma unroll
        for (int i = 0; i < 4; i++) {
            const int r = i * 32 + stg_r;
            __builtin_amdgcn_global_load_lds(
                (const __attribute__((address_space(1))) void*)(Bp + (long)(bn0 + r) * K + kt + stg_cg),
                (__attribute__((address_space(3))) void*)(Bs + r * BK + stg_cl),
                16, 0, 0);
        }
        // A: bf16 async, or fp32 load+cvt+ds_write (same swizzled slots)
        if (!aF32) {
#pragma unroll
            for (int i = 0; i < 4; i++) {
                const int r = i * 32 + stg_r;
                __builtin_amdgcn_global_load_lds(
                    (const __attribute__((address_space(1))) void*)(Ab + (long)(bm0 + r) * K + kt + stg_cg),
                    (__attribute__((address_space(3))) void*)(As + r * BK + stg_cl),
                    16, 0, 0);
            }
        } else {
#pragma unroll
            for (int i = 0; i < 4; i++) {
                const int r = i * 32 + stg_r;
                const float* s = A32 + (long)(bm0 + r) * K + kt + stg_cg;
                float4 f0 = *(const float4*)s;
                float4 f1 = *(const float4*)(s + 4);
                uint4 pk;
                pk.x = (unsigned)f2b(f0.x) | ((unsigned)f2b(f0.y) << 16);
                pk.y = (unsigned)f2b(f0.z) | ((unsigned)f2b(f0.w) << 16);
                pk.z = (unsigned)f2b(f1.x) | ((unsigned)f2b(f1.y) << 16);
                pk.w = (unsigned)f2b(f1.z) | ((unsigned)f2b(f1.w) << 16);
                *(uint4*)(As + r * BK + stg_cl) = pk;
            }
        }
        __syncthreads();

#pragma unroll
        for (int kk = 0; kk < 2; kk++) {
            bf16x8 af[4], bb[4];
#pragma unroll
            for (int t = 0; t < 4; t++)
                af[t] = *(const bf16x8*)(As + (wm * 64 + t * 16 + l15) * BK
                                             + (((kk * 4 + quad) ^ sw) * 8));
#pragma unroll
            for (int t = 0; t < 4; t++)
                bb[t] = *(const bf16x8*)(Bs + (wn * 64 + t * 16 + l15) * BK
                                             + (((kk * 4 + quad) ^ sw) * 8));
#pragma unroll
            for (int mt = 0; mt < 4; mt++)
#pragma unroll
                for (int nt = 0; nt < 4; nt++)
                    acc[mt][nt] = __builtin_amdgcn_mfma_f32_16x16x32_bf16(
                        af[mt], bb[nt], acc[mt][nt], 0, 0, 0);
        }
        __syncthreads();
    }

    // epilogue; C/D layout: col = lane&15, row = quad*4 + reg (m89/m91)
#pragma unroll
    for (int mt = 0; mt < 4; mt++) {
        const int row = bm0 + wm * 64 + mt * 16 + quad * 4;
#pragma unroll
        for (int nt = 0; nt < 4; nt++) {
            const int col = bn0 + wn * 64 + nt * 16 + l15;
            const float bv = bias ? b2f(bias[col]) : 0.f;
            f32x4 v = acc[mt][nt];
            float o0 = alpha * v[0] + bv;
            float o1 = alpha * v[1] + bv;
            float o2 = alpha * v[2] + bv;
            float o3 = alpha * v[3] + bv;
            if (em == 2) {
                ushort4 pk;
                pk.x = f2b(o0); pk.y = f2b(o1); pk.z = f2b(o2); pk.w = f2b(o3);
                *(ushort4*)((u16*)C + coff + ((long)(row >> 11) << 21) + ((long)col << 11) + (row & 2047)) = pk;
            } else if (em == 1) {
                float* Cf = (float*)C + coff;
                Cf[(long)(row + 0) * ldc + col] = o0;
                Cf[(long)(row + 1) * ldc + col] = o1;
                Cf[(long)(row + 2) * ldc + col] = o2;
                Cf[(long)(row + 3) * ldc + col] = o3;
            } else {
                u16* Cb = (u16*)C + coff;
                Cb[(long)(row + 0) * ldc + col] = f2b(o0);
                Cb[(long)(row + 1) * ldc + col] = f2b(o1);
                Cb[(long)(row + 2) * ldc + col] = f2b(o2);
                Cb[(long)(row + 3) * ldc + col] = f2b(o3);
            }
        }
    }
}

// in-place softmax over rows of 2048 bf16; one block (256 thr) per row
__global__ __launch_bounds__(256)
void softmax_rows(u16* __restrict__ S)
{
    const long row = blockIdx.x;
    u16* p = S + (row << 11);
    const int tid = threadIdx.x, wave = tid >> 6, lane = tid & 63;

    union { uint4 q; u16 u[8]; } d;
    d.q = ((const uint4*)p)[tid];
    float v[8];
#pragma unroll
    for (int i = 0; i < 8; i++) v[i] = b2f(d.u[i]);

    float m = v[0];
#pragma unroll
    for (int i = 1; i < 8; i++) m = fmaxf(m, v[i]);
#pragma unroll
    for (int o = 32; o; o >>= 1) m = fmaxf(m, __shfl_xor(m, o, 64));
    __shared__ float redm[4], reds[4];
    if (lane == 0) redm[wave] = m;
    __syncthreads();
    m = fmaxf(fmaxf(redm[0], redm[1]), fmaxf(redm[2], redm[3]));

    float e[8], s = 0.f;
#pragma unroll
    for (int i = 0; i < 8; i++) { e[i] = __expf(v[i] - m); s += e[i]; }
#pragma unroll
    for (int o = 32; o; o >>= 1) s += __shfl_xor(s, o, 64);
    if (lane == 0) reds[wave] = s;
    __syncthreads();
    s = reds[0] + reds[1] + reds[2] + reds[3];

    const float inv = 1.f / s;
#pragma unroll
    for (int i = 0; i < 8; i++) d.u[i] = f2b(e[i] * inv);
    ((uint4*)p)[tid] = d.q;
}

extern "C" void kernel_launch(void* const* d_in, const int* in_sizes, int n_in,
                              void* d_out, int out_size, void* d_ws, size_t ws_size,
                              hipStream_t stream) {
    const float* query = (const float*)d_in[0];   // (8,2048,1024) fp32
    const float* key   = (const float*)d_in[1];
    const float* value = (const float*)d_in[2];
    const float* W     = (const float*)d_in[3];   // (1024,1024) fp32 (P,E)
    const float* bias  = (const float*)d_in[4];   // (1024,) fp32
    float* out = (float*)d_out;                   // (8,2048,1024) fp32

    // ws (u16 elems), 167.8 MB:
    //   [0, 33.5M)  sc (scores) | aliased early: Wc @16.7M, bc after
    //   [33.5M..)   qb | kb | vT  (3 x 16.7M, contiguous — mode5 relies on it)
    u16* sc  = (u16*)d_ws;
    u16* Wc  = (u16*)d_ws + 16777216L;
    u16* bc  = Wc + 1048576L;
    u16* qb  = (u16*)d_ws + 33554432L;
    u16* kb  = qb + 16777216L;
    u16* vT  = kb + 16777216L;

    const dim3 blk(256);

    convert_f32_bf16<<<dim3(512), blk, 0, stream>>>(W, Wc, 1048576L);
    convert_f32_bf16<<<dim3(1), blk, 0, stream>>>(bias, bc, 1024L);

    // merged projections: per z: M=16384, N=1024, K=1024, fp32 A.
    // XCD patch 8x16: all 8 bx sharing an A-panel stay on one XCD.
    gemm_nt<<<dim3(8, 128, 3), blk, 0, stream>>>(query, key, value, Wc, qb, bc,
        1024, 1.f, 5, 1024, 0, 0, 16777216L, 8, 16);

    // scores: per batch, M=N=2048, K=1024, alpha=1/32; XCD patch 8x4
    gemm_nt<<<dim3(16, 16, 8), blk, 0, stream>>>(qb, nullptr, nullptr, kb, sc, nullptr,
        1024, 0.03125f, 0, 2048, 2048L * 1024, 2048L * 1024, 2048L * 2048, 8, 4);

    // softmax rows (8*2048), in place
    softmax_rows<<<dim3(16384), blk, 0, stream>>>(sc);

    // out = S @ vT^T: per batch, M=2048, N=1024, K=2048, fp32 C; XCD patch 4x4
    gemm_nt<<<dim3(8, 16, 8), blk, 0, stream>>>(sc, nullptr, nullptr, vT, out, nullptr,
        2048, 1.f, 1, 1024, 2048L * 2048, 1024L * 2048, 2048L * 1024, 4, 4);
}